// Round 6
// baseline (426.716 us; speedup 1.0000x reference)
//
#include <hip/hip_runtime.h>
#include <stdint.h>

typedef unsigned short ushort_t;
typedef __attribute__((ext_vector_type(8))) short short8;
typedef __attribute__((ext_vector_type(8))) unsigned short ushortx8;
typedef __attribute__((ext_vector_type(4))) float floatx4;

#define B_    32
#define C_    256
#define O_    256
#define HID_  65
#define HW_   4096
#define KDIM  2304          // C_ * 9
#define XP_H  66            // padded spatial edge
#define XPAD_ELEMS ((size_t)B_ * XP_H * XP_H * C_)   // 35,684,352 bf16
#define WAGG_ELEMS ((size_t)B_ * O_ * KDIM)          // 18,874,368 bf16

static __device__ __forceinline__ unsigned short f2bf(float f) {
  unsigned u = __float_as_uint(f);
  u += 0x7fffu + ((u >> 16) & 1u);        // RNE
  return (unsigned short)(u >> 16);
}

static __device__ __forceinline__ void gld_lds16(const void* g, void* l) {
  // async global->LDS, 16B/lane; LDS dest = wave-uniform base + lane*16
  __builtin_amdgcn_global_load_lds((__attribute__((address_space(1))) void*)(g),
                                   (__attribute__((address_space(3))) void*)(l),
                                   16, 0, 0);
}

#define FENCE() __builtin_amdgcn_sched_barrier(0)
#define BAR()   __builtin_amdgcn_s_barrier()

// ----------------------------------------------------------------- pad ------
// xpad[b][h+1][w+1][c] (bf16, HWC) from x[b][c][h][w] (fp32, CHW), PLUS
// per-block pooling partials, PLUS (cT==0 blocks) zeroing the pad border.
__global__ void pad_kernel(const float* __restrict__ x, ushort_t* __restrict__ xpad,
                           float* __restrict__ partial) {
  __shared__ float tileT[64][65];                  // [hw][c], 16.6 KB
  __shared__ float pool[4][64];
  const int hwT = blockIdx.x, cT = blockIdx.y, b = blockIdx.z;
  const int t = threadIdx.x;
  const int hw0 = hwT * 64, c0 = cT * 64;
  const float* src = x + ((size_t)(b * C_ + c0)) * HW_ + hw0;

  // border fusion: 8320 uint4 per b, spread over the 64 cT==0 blocks.
  if (cT == 0) {
    const int tid = hwT * 256 + t;
    if (tid < 8320) {
      uint4 z = {0u, 0u, 0u, 0u};
      uint4* base = (uint4*)(xpad + (size_t)b * XP_H * XP_H * C_);
      size_t idx;
      if (tid < 2112) idx = (size_t)tid;                               // h=0
      else if (tid < 4224) idx = (size_t)65 * 2112 + (tid - 2112);     // h=65
      else if (tid < 6272) {                                           // w=0
        const int i = tid - 4224;
        idx = (size_t)(1 + (i >> 5)) * 2112 + (i & 31);
      } else {                                                         // w=65
        const int i = tid - 6272;
        idx = (size_t)(1 + (i >> 5)) * 2112 + 65 * 32 + (i & 31);
      }
      base[idx] = z;
    }
  }

  // load: 64c x 64hw = 1024 float4; 4 per thread. lanes sweep hw -> coalesced.
#pragma unroll
  for (int p = 0; p < 4; ++p) {
    const int flat = p * 256 + t;
    const int c = flat >> 4, h4 = (flat & 15) * 4;
    const float4 v = *(const float4*)(src + (size_t)c * HW_ + h4);
    tileT[h4 + 0][c] = v.x;                        // banks -> 2-way, free
    tileT[h4 + 1][c] = v.y;
    tileT[h4 + 2][c] = v.z;
    tileT[h4 + 3][c] = v.w;
  }
  __syncthreads();

  // pooling: thread owns (qh,c); banks -> 2-way, free.
  {
    const int c = t & 63, qh = t >> 6;
    float s = 0.f;
#pragma unroll
    for (int i = 0; i < 16; ++i) s += tileT[qh * 16 + i][c];
    pool[qh][c] = s;
  }
  __syncthreads();
  if (t < 64) {
    partial[(size_t)hwT * (B_ * C_) + b * C_ + c0 + t] =
        pool[0][t] + pool[1][t] + pool[2][t] + pool[3][t];
  }

  // store: ushort8 per thread (16 B/lane; 8x128B segments per wave-inst).
#pragma unroll
  for (int p = 0; p < 2; ++p) {
    const int flat = p * 256 + t;
    const int hw = flat >> 3, cg = (flat & 7) * 8;
    ushortx8 v;
#pragma unroll
    for (int j = 0; j < 8; ++j) v[j] = f2bf(tileT[hw][cg + j]);
    const int h = (hw0 + hw) >> 6, w = (hw0 + hw) & 63;
    *(ushortx8*)(xpad + (((size_t)b * XP_H + (h + 1)) * XP_H + (w + 1)) * C_ + c0 + cg) = v;
  }
}

// ---------------------------------------------------------------- attn ------
__global__ void attn_kernel(const float* __restrict__ partial,
                            const float* __restrict__ w1,
                            const float* __restrict__ w2,
                            const float* __restrict__ b2,
                            float* __restrict__ attn) {
  __shared__ float sp[C_];
  __shared__ float sh[HID_];
  const int b = blockIdx.x, t = threadIdx.x;
  {
    float s = 0.f;
#pragma unroll
    for (int i = 0; i < 64; ++i) s += partial[(size_t)i * (B_ * C_) + b * C_ + t];
    sp[t] = s * (1.f / 4096.f);
  }
  __syncthreads();
  if (t < HID_) {
    float a = 0.f;
    for (int c = 0; c < C_; ++c) a += sp[c] * w1[t * C_ + c];
    sh[t] = fmaxf(a, 0.f);
  }
  __syncthreads();
  float lg[4];
#pragma unroll
  for (int k = 0; k < 4; ++k) {
    float a = b2[k * O_ + t];
    for (int j = 0; j < HID_; ++j) a += sh[j] * w2[(k * O_ + t) * HID_ + j];
    lg[k] = a * 2.0f;                              // / TEMP (0.5)
  }
  float mx = fmaxf(fmaxf(lg[0], lg[1]), fmaxf(lg[2], lg[3]));
  float e0 = expf(lg[0] - mx), e1 = expf(lg[1] - mx);
  float e2 = expf(lg[2] - mx), e3 = expf(lg[3] - mx);
  float inv = 1.f / (e0 + e1 + e2 + e3);
  attn[(b * 4 + 0) * O_ + t] = e0 * inv;
  attn[(b * 4 + 1) * O_ + t] = e1 * inv;
  attn[(b * 4 + 2) * O_ + t] = e2 * inv;
  attn[(b * 4 + 3) * O_ + t] = e3 * inv;
}

// ----------------------------------------------------------------- agg ------
// Register-cached wt (36 contiguous floats/thread) + b-split for occupancy.
__global__ void agg_kernel(const float* __restrict__ attn,
                           const float* __restrict__ wt,
                           ushort_t* __restrict__ wagg) {
  const int o = blockIdx.x;
  const int b0 = blockIdx.y * 4;                   // 8 groups x 4 b
  const int t = threadIdx.x;                       // = c
  float wr[4][9];
#pragma unroll
  for (int k = 0; k < 4; ++k) {
    const float* src = wt + (size_t)(k * O_ + o) * KDIM + t * 9;
#pragma unroll
    for (int n = 0; n < 9; ++n) wr[k][n] = src[n];
  }
#pragma unroll
  for (int bi = 0; bi < 4; ++bi) {
    const int b = b0 + bi;
    const float a0 = attn[(b * 4 + 0) * O_ + o];
    const float a1 = attn[(b * 4 + 1) * O_ + o];
    const float a2 = attn[(b * 4 + 2) * O_ + o];
    const float a3 = attn[(b * 4 + 3) * O_ + o];
    ushort_t* dst = wagg + (size_t)(b * O_ + o) * KDIM;
#pragma unroll
    for (int n = 0; n < 9; ++n) {
      float v = a0 * wr[0][n] + a1 * wr[1][n] + a2 * wr[2][n] + a3 * wr[3][n];
      dst[n * C_ + t] = f2bf(v);
    }
  }
}

// ---------------------------------------------------------------- gemm ------
// 256(o) x 256(hw), BK=64, 8 waves (2M x 4N), dbuf 128 KiB LDS, fine
// 4-phase/K-tile schedule with counted vmcnt — round 6: MINIMAL fences.
// Round 5 pinned every phase with sched_barrier(0) pairs (24/K-tile) — the
// documented m141 failure (order-pinning defeats the compiler's own
// interleave). Now only the hazard-required set remains:
//   - FENCE at p0/p3 top (before stage-issues): earlier phases' ds_reads of
//     rows about to be overwritten cannot sink below the staging writes.
//   - FENCE after each mid-BAR: MFMA cluster (pure, hoistable) stays below
//     its lockstep barrier, preserving the phase structure.
//   - FENCE after p3's vmcnt+BAR: next tile's ds_reads cannot hoist above
//     the wait that guarantees their buffer landed.
// Everything else (incl. all lgkmcnt(0) drains) is left to the scheduler so
// next-phase ds_reads can slide into the current MFMA cluster (m196's fine
// interleave — the actual 8-phase lever).
__global__ __launch_bounds__(512) void gemm_kernel(const ushort_t* __restrict__ xpad,
                                                   const ushort_t* __restrict__ wagg,
                                                   float* __restrict__ out) {
  __shared__ short lA0[2 * 256 * 64];              // 64 KB (2 bufs)
  __shared__ short lB0[2 * 256 * 64];              // 64 KB

  const int bid = blockIdx.x;                      // 0..511
  const int xcd = bid & 7;
  const int q   = bid >> 3;
  const int b   = xcd + ((q >> 4) << 3);
  const int hwT = q & 15;
  const int hwBase = hwT << 8;
  const int h0     = hwT << 2;                     // 4 image rows per tile

  const int t    = threadIdx.x;
  const int lane = t & 63;
  const int wv   = t >> 6;                         // 0..7

  // staging: call j covers contiguous rows [j*64, j*64+64); wave wv owns
  // rows j*64 + wv*8 + rS. physical 16B slot = pS, logical chunk = pS^rS.
  const int rS  = lane >> 3;
  const int pS  = lane & 7;
  const int lch = pS ^ rS;                         // row&7 == rS for all calls
  size_t aG2[4], bG2[4];
  int sOff[4];
#pragma unroll
  for (int j = 0; j < 4; ++j) {
    const int row = j * 64 + wv * 8 + rS;
    aG2[j] = (size_t)(b * O_ + row) * KDIM + lch * 8;
    bG2[j] = ((size_t)(b * XP_H + h0 + j) * XP_H + (wv * 8 + rS)) * C_ + lch * 8;
    sOff[j] = (j * 64 + wv * 8) * 64;              // shorts
  }

  // fragment geometry (mfma_f32_16x16x32_bf16)
  const int lm   = lane & 15;
  const int quad = lane >> 4;
  const int mW   = (wv >> 2) << 7;                 // o base: 0/128
  const int nW   = (wv & 3) << 6;                  // hw base: 0..192
  int aBase[2], bBase[2];
#pragma unroll
  for (int h = 0; h < 2; ++h) {
    const int ps = ((h * 4 + quad) ^ (lm & 7)) * 8;     // de-swizzle, shorts
    aBase[h] = (mW + lm) * 64 + ps;
    bBase[h] = (nW + lm) * 64 + ps;
  }

  auto stageA = [&](int j, int kt, short* dst) {
    gld_lds16(wagg + aG2[j] + ((size_t)kt << 6), dst + sOff[j]);
  };
  auto stageB = [&](int j, int kt, short* dst) {
    const int tap = kt >> 2;
    const size_t off = (size_t)((tap / 3) * XP_H + (tap % 3)) * C_ + ((kt & 3) << 6);
    gld_lds16(xpad + bG2[j] + off, dst + sOff[j]);
  };

  floatx4 acc[8][4] = {};

  // ---- prologue: tile0 full (8 calls) -> buf0; tile1 {A0,A2,B0-3} -> buf1
#pragma unroll
  for (int j = 0; j < 4; ++j) {
    stageA(j, 0, lA0);
    stageB(j, 0, lB0);
  }
  stageA(0, 1, lA0 + 16384);
  stageA(2, 1, lA0 + 16384);
#pragma unroll
  for (int j = 0; j < 4; ++j) stageB(j, 1, lB0 + 16384);
  __builtin_amdgcn_s_waitcnt(0x0f76);              // vmcnt(6): tile0 landed
  BAR();
  FENCE();

#pragma unroll 1
  for (int tt = 0; tt < 36; ++tt) {
    const int cb = (tt & 1) << 14;                 // buffer offset (shorts)
    const short* bufA = lA0 + cb;
    const short* bufB = lB0 + cb;
    short* oA = lA0 + (cb ^ 16384);
    short8 af[4], bf[4];

    // -------- p0: af(mi0-3,h0)+bf(h0); stage tt+1 {A1,A3} -> other --------
    FENCE();                                       // prior reads stay above stage
#pragma unroll
    for (int i = 0; i < 4; ++i) af[i] = *(const short8*)(bufA + aBase[0] + i * 1024);
#pragma unroll
    for (int i = 0; i < 4; ++i) bf[i] = *(const short8*)(bufB + bBase[0] + i * 1024);
    if (tt < 35) {
      stageA(1, tt + 1, oA);
      stageA(3, tt + 1, oA);
    }
    BAR(); FENCE();
    __builtin_amdgcn_s_setprio(1);
#pragma unroll
    for (int mi = 0; mi < 4; ++mi)
#pragma unroll
      for (int ni = 0; ni < 4; ++ni)
        acc[mi][ni] = __builtin_amdgcn_mfma_f32_16x16x32_bf16(af[mi], bf[ni], acc[mi][ni], 0, 0, 0);
    __builtin_amdgcn_s_setprio(0);
    BAR();

    // -------- p1: af(mi4-7,h0) ------------------------------------------
#pragma unroll
    for (int i = 0; i < 4; ++i) af[i] = *(const short8*)(bufA + aBase[0] + (4 + i) * 1024);
    BAR(); FENCE();
    __builtin_amdgcn_s_setprio(1);
#pragma unroll
    for (int mi = 0; mi < 4; ++mi)
#pragma unroll
      for (int ni = 0; ni < 4; ++ni)
        acc[4 + mi][ni] = __builtin_amdgcn_mfma_f32_16x16x32_bf16(af[mi], bf[ni], acc[4 + mi][ni], 0, 0, 0);
    __builtin_amdgcn_s_setprio(0);
    BAR();

    // -------- p2: af(mi0-3,h1)+bf(h1) -----------------------------------
#pragma unroll
    for (int i = 0; i < 4; ++i) af[i] = *(const short8*)(bufA + aBase[1] + i * 1024);
#pragma unroll
    for (int i = 0; i < 4; ++i) bf[i] = *(const short8*)(bufB + bBase[1] + i * 1024);
    BAR(); FENCE();
    __builtin_amdgcn_s_setprio(1);
#pragma unroll
    for (int mi = 0; mi < 4; ++mi)
#pragma unroll
      for (int ni = 0; ni < 4; ++ni)
        acc[mi][ni] = __builtin_amdgcn_mfma_f32_16x16x32_bf16(af[mi], bf[ni], acc[mi][ni], 0, 0, 0);
    __builtin_amdgcn_s_setprio(0);
    BAR();

    // -------- p3: af(mi4-7,h1); stage tt+2 {A0,A2,B0-3} -> this buf ------
    FENCE();                                       // p2 reads stay above stage
#pragma unroll
    for (int i = 0; i < 4; ++i) af[i] = *(const short8*)(bufA + aBase[1] + (4 + i) * 1024);
    if (tt < 34) {
      stageA(0, tt + 2, lA0 + cb);
      stageA(2, tt + 2, lA0 + cb);
#pragma unroll
      for (int j = 0; j < 4; ++j) stageB(j, tt + 2, lB0 + cb);
    }
    BAR(); FENCE();
    __builtin_amdgcn_s_setprio(1);
#pragma unroll
    for (int mi = 0; mi < 4; ++mi)
#pragma unroll
      for (int ni = 0; ni < 4; ++ni)
        acc[4 + mi][ni] = __builtin_amdgcn_mfma_f32_16x16x32_bf16(af[mi], bf[ni], acc[4 + mi][ni], 0, 0, 0);
    __builtin_amdgcn_s_setprio(0);
    if (tt < 34)       __builtin_amdgcn_s_waitcnt(0x0f76);  // vmcnt(6)
    else if (tt == 34) __builtin_amdgcn_s_waitcnt(0x0f70);  // vmcnt(0)
    if (tt < 35) { BAR(); FENCE(); }               // next tile's reads below
  }

  // epilogue: D row(o) = quad*4 + r, col(hw) = lane&15  [verified m89/m91]
  const size_t outBase = (size_t)b * O_ * HW_;
#pragma unroll
  for (int mi = 0; mi < 8; ++mi) {
#pragma unroll
    for (int ni = 0; ni < 4; ++ni) {
      const int hw = hwBase + nW + ni * 16 + lm;
#pragma unroll
      for (int r = 0; r < 4; ++r) {
        const int o = mW + mi * 16 + quad * 4 + r;
        out[outBase + (size_t)o * HW_ + hw] = acc[mi][ni][r];
      }
    }
  }
}

// -------------------------------------------------------------- launch ------
extern "C" void kernel_launch(void* const* d_in, const int* in_sizes, int n_in,
                              void* d_out, int out_size, void* d_ws, size_t ws_size,
                              hipStream_t stream) {
  const float* x  = (const float*)d_in[0];   // [32,256,64,64]
  const float* w1 = (const float*)d_in[1];   // [65,256]
  const float* w2 = (const float*)d_in[2];   // [1024,65]
  const float* b2 = (const float*)d_in[3];   // [1024]
  const float* wt = (const float*)d_in[4];   // [4,256,256,3,3]
  float* out = (float*)d_out;                // [32,256,64,64]

  char* ws = (char*)d_ws;
  ushort_t* xpad = (ushort_t*)ws;                                  // 71.4 MB
  ushort_t* wagg = (ushort_t*)(ws + XPAD_ELEMS * 2);               // 37.7 MB
  float* partial = (float*)(ws + XPAD_ELEMS * 2 + WAGG_ELEMS * 2); // 2 MB
  float* attn    = partial + 64 * B_ * C_;                         // 128 KB

  pad_kernel<<<dim3(64, 4, B_), 256, 0, stream>>>(x, xpad, partial);
  attn_kernel<<<B_, 256, 0, stream>>>(partial, w1, w2, b2, attn);
  agg_kernel<<<dim3(O_, 8), 256, 0, stream>>>(attn, wt, wagg);
  gemm_kernel<<<512, 512, 0, stream>>>(xpad, wagg, out);
}

// Round 7
// 414.691 us; speedup vs baseline: 1.0290x; 1.0290x over previous
//
#include <hip/hip_runtime.h>
#include <stdint.h>

typedef unsigned short ushort_t;
typedef __attribute__((ext_vector_type(8))) short short8;
typedef __attribute__((ext_vector_type(8))) unsigned short ushortx8;
typedef __attribute__((ext_vector_type(4))) float floatx4;

#define B_    32
#define C_    256
#define O_    256
#define HID_  65
#define HW_   4096
#define KDIM  2304          // C_ * 9
#define XP_H  66            // padded spatial edge
#define XPAD_ELEMS ((size_t)B_ * XP_H * XP_H * C_)   // 35,684,352 bf16
#define WAGG_ELEMS ((size_t)B_ * O_ * KDIM)          // 18,874,368 bf16

static __device__ __forceinline__ unsigned short f2bf(float f) {
  unsigned u = __float_as_uint(f);
  u += 0x7fffu + ((u >> 16) & 1u);        // RNE
  return (unsigned short)(u >> 16);
}

static __device__ __forceinline__ void gld_lds16(const void* g, void* l) {
  // async global->LDS, 16B/lane; LDS dest = wave-uniform base + lane*16
  __builtin_amdgcn_global_load_lds((__attribute__((address_space(1))) void*)(g),
                                   (__attribute__((address_space(3))) void*)(l),
                                   16, 0, 0);
}

#define FENCE() __builtin_amdgcn_sched_barrier(0)
#define BAR()   __builtin_amdgcn_s_barrier()

// ----------------------------------------------------------------- pad ------
// xpad[b][h+1][w+1][c] (bf16, HWC) from x[b][c][h][w] (fp32, CHW), PLUS
// per-block pooling partials, PLUS (cT==0 blocks) zeroing the pad border.
__global__ void pad_kernel(const float* __restrict__ x, ushort_t* __restrict__ xpad,
                           float* __restrict__ partial) {
  __shared__ float tileT[64][65];                  // [hw][c], 16.6 KB
  __shared__ float pool[4][64];
  const int hwT = blockIdx.x, cT = blockIdx.y, b = blockIdx.z;
  const int t = threadIdx.x;
  const int hw0 = hwT * 64, c0 = cT * 64;
  const float* src = x + ((size_t)(b * C_ + c0)) * HW_ + hw0;

  // border fusion: 8320 uint4 per b, spread over the 64 cT==0 blocks.
  if (cT == 0) {
    const int tid = hwT * 256 + t;
    if (tid < 8320) {
      uint4 z = {0u, 0u, 0u, 0u};
      uint4* base = (uint4*)(xpad + (size_t)b * XP_H * XP_H * C_);
      size_t idx;
      if (tid < 2112) idx = (size_t)tid;                               // h=0
      else if (tid < 4224) idx = (size_t)65 * 2112 + (tid - 2112);     // h=65
      else if (tid < 6272) {                                           // w=0
        const int i = tid - 4224;
        idx = (size_t)(1 + (i >> 5)) * 2112 + (i & 31);
      } else {                                                         // w=65
        const int i = tid - 6272;
        idx = (size_t)(1 + (i >> 5)) * 2112 + 65 * 32 + (i & 31);
      }
      base[idx] = z;
    }
  }

  // load: 64c x 64hw = 1024 float4; 4 per thread. lanes sweep hw -> coalesced.
#pragma unroll
  for (int p = 0; p < 4; ++p) {
    const int flat = p * 256 + t;
    const int c = flat >> 4, h4 = (flat & 15) * 4;
    const float4 v = *(const float4*)(src + (size_t)c * HW_ + h4);
    tileT[h4 + 0][c] = v.x;                        // banks -> 2-way, free
    tileT[h4 + 1][c] = v.y;
    tileT[h4 + 2][c] = v.z;
    tileT[h4 + 3][c] = v.w;
  }
  __syncthreads();

  // pooling: thread owns (qh,c); banks -> 2-way, free.
  {
    const int c = t & 63, qh = t >> 6;
    float s = 0.f;
#pragma unroll
    for (int i = 0; i < 16; ++i) s += tileT[qh * 16 + i][c];
    pool[qh][c] = s;
  }
  __syncthreads();
  if (t < 64) {
    partial[(size_t)hwT * (B_ * C_) + b * C_ + c0 + t] =
        pool[0][t] + pool[1][t] + pool[2][t] + pool[3][t];
  }

  // store: ushort8 per thread (16 B/lane; 8x128B segments per wave-inst).
#pragma unroll
  for (int p = 0; p < 2; ++p) {
    const int flat = p * 256 + t;
    const int hw = flat >> 3, cg = (flat & 7) * 8;
    ushortx8 v;
#pragma unroll
    for (int j = 0; j < 8; ++j) v[j] = f2bf(tileT[hw][cg + j]);
    const int h = (hw0 + hw) >> 6, w = (hw0 + hw) & 63;
    *(ushortx8*)(xpad + (((size_t)b * XP_H + (h + 1)) * XP_H + (w + 1)) * C_ + c0 + cg) = v;
  }
}

// ---------------------------------------------------------------- attn ------
__global__ void attn_kernel(const float* __restrict__ partial,
                            const float* __restrict__ w1,
                            const float* __restrict__ w2,
                            const float* __restrict__ b2,
                            float* __restrict__ attn) {
  __shared__ float sp[C_];
  __shared__ float sh[HID_];
  const int b = blockIdx.x, t = threadIdx.x;
  {
    float s = 0.f;
#pragma unroll
    for (int i = 0; i < 64; ++i) s += partial[(size_t)i * (B_ * C_) + b * C_ + t];
    sp[t] = s * (1.f / 4096.f);
  }
  __syncthreads();
  if (t < HID_) {
    float a = 0.f;
    for (int c = 0; c < C_; ++c) a += sp[c] * w1[t * C_ + c];
    sh[t] = fmaxf(a, 0.f);
  }
  __syncthreads();
  float lg[4];
#pragma unroll
  for (int k = 0; k < 4; ++k) {
    float a = b2[k * O_ + t];
    for (int j = 0; j < HID_; ++j) a += sh[j] * w2[(k * O_ + t) * HID_ + j];
    lg[k] = a * 2.0f;                              // / TEMP (0.5)
  }
  float mx = fmaxf(fmaxf(lg[0], lg[1]), fmaxf(lg[2], lg[3]));
  float e0 = expf(lg[0] - mx), e1 = expf(lg[1] - mx);
  float e2 = expf(lg[2] - mx), e3 = expf(lg[3] - mx);
  float inv = 1.f / (e0 + e1 + e2 + e3);
  attn[(b * 4 + 0) * O_ + t] = e0 * inv;
  attn[(b * 4 + 1) * O_ + t] = e1 * inv;
  attn[(b * 4 + 2) * O_ + t] = e2 * inv;
  attn[(b * 4 + 3) * O_ + t] = e3 * inv;
}

// ----------------------------------------------------------------- agg ------
// Register-cached wt (36 contiguous floats/thread) + b-split for occupancy.
__global__ void agg_kernel(const float* __restrict__ attn,
                           const float* __restrict__ wt,
                           ushort_t* __restrict__ wagg) {
  const int o = blockIdx.x;
  const int b0 = blockIdx.y * 4;                   // 8 groups x 4 b
  const int t = threadIdx.x;                       // = c
  float wr[4][9];
#pragma unroll
  for (int k = 0; k < 4; ++k) {
    const float* src = wt + (size_t)(k * O_ + o) * KDIM + t * 9;
#pragma unroll
    for (int n = 0; n < 9; ++n) wr[k][n] = src[n];
  }
#pragma unroll
  for (int bi = 0; bi < 4; ++bi) {
    const int b = b0 + bi;
    const float a0 = attn[(b * 4 + 0) * O_ + o];
    const float a1 = attn[(b * 4 + 1) * O_ + o];
    const float a2 = attn[(b * 4 + 2) * O_ + o];
    const float a3 = attn[(b * 4 + 3) * O_ + o];
    ushort_t* dst = wagg + (size_t)(b * O_ + o) * KDIM;
#pragma unroll
    for (int n = 0; n < 9; ++n) {
      float v = a0 * wr[0][n] + a1 * wr[1][n] + a2 * wr[2][n] + a3 * wr[3][n];
      dst[n * C_ + t] = f2bf(v);
    }
  }
}

// ---------------------------------------------------------------- gemm ------
// 256(o) x 256(hw), BK=64, 8 waves (2M x 4N), dbuf 128 KiB LDS, counted
// vmcnt. Round 7: FREE-SLIP schedule — only the hazard-required barriers:
//   [p0: reads A0A2(h0)+B(h0), stage tt+1{A1,A3}->other, 16 MFMA]
//   [p1: reads A1A3(h0),                                 16 MFMA]   free
//   [p2: reads A0A2(h1)+B(h1),                           16 MFMA]   region
//   BAR  (all waves done reading cb's A0/A2/B -> p3 may overwrite them)
//   [p3: reads A1A3(h1); stage tt+2{A0,A2,B}->cb; vmcnt(6); 16 MFMA]
//   BAR  (tt+1's buffer landed for everyone)
// 3 barriers/tile (vs 8). Waves drift apart inside the free region so one
// wave's ds_reads/stages overlap another's MFMAs — the intra-block analog
// of the 128-tile cross-block overlap (impossible before under lockstep).
// vmcnt(6) sits BEFORE p3's MFMA cluster so 16 MFMAs cover residual load
// latency; FENCE after it (rule #18: MFMAs must not hoist above the wait).
// Staging invariant unchanged: tile v = {A0,A2,B} at (v-2)p3 + {A1,A3} at
// (v-1)p0; at (v-1)p3's wait, outstanding = v's 8 + (v+1)'s 6 -> vmcnt(6)
// retires exactly tile v.
__global__ __launch_bounds__(512) void gemm_kernel(const ushort_t* __restrict__ xpad,
                                                   const ushort_t* __restrict__ wagg,
                                                   float* __restrict__ out) {
  __shared__ short lA0[2 * 256 * 64];              // 64 KB (2 bufs)
  __shared__ short lB0[2 * 256 * 64];              // 64 KB

  const int bid = blockIdx.x;                      // 0..511
  const int xcd = bid & 7;
  const int q   = bid >> 3;
  const int b   = xcd + ((q >> 4) << 3);
  const int hwT = q & 15;
  const int hwBase = hwT << 8;
  const int h0     = hwT << 2;                     // 4 image rows per tile

  const int t    = threadIdx.x;
  const int lane = t & 63;
  const int wv   = t >> 6;                         // 0..7

  // staging: call j covers contiguous rows [j*64, j*64+64); wave wv owns
  // rows j*64 + wv*8 + rS. physical 16B slot = pS, logical chunk = pS^rS.
  const int rS  = lane >> 3;
  const int pS  = lane & 7;
  const int lch = pS ^ rS;                         // row&7 == rS for all calls
  size_t aG2[4], bG2[4];
  int sOff[4];
#pragma unroll
  for (int j = 0; j < 4; ++j) {
    const int row = j * 64 + wv * 8 + rS;
    aG2[j] = (size_t)(b * O_ + row) * KDIM + lch * 8;
    bG2[j] = ((size_t)(b * XP_H + h0 + j) * XP_H + (wv * 8 + rS)) * C_ + lch * 8;
    sOff[j] = (j * 64 + wv * 8) * 64;              // shorts
  }

  // fragment geometry (mfma_f32_16x16x32_bf16)
  const int lm   = lane & 15;
  const int quad = lane >> 4;
  const int mW   = (wv >> 2) << 7;                 // o base: 0/128
  const int nW   = (wv & 3) << 6;                  // hw base: 0..192
  int aBase[2], bBase[2];
#pragma unroll
  for (int h = 0; h < 2; ++h) {
    const int ps = ((h * 4 + quad) ^ (lm & 7)) * 8;     // de-swizzle, shorts
    aBase[h] = (mW + lm) * 64 + ps;
    bBase[h] = (nW + lm) * 64 + ps;
  }

  auto stageA = [&](int j, int kt, short* dst) {
    gld_lds16(wagg + aG2[j] + ((size_t)kt << 6), dst + sOff[j]);
  };
  auto stageB = [&](int j, int kt, short* dst) {
    const int tap = kt >> 2;
    const size_t off = (size_t)((tap / 3) * XP_H + (tap % 3)) * C_ + ((kt & 3) << 6);
    gld_lds16(xpad + bG2[j] + off, dst + sOff[j]);
  };

  floatx4 acc[8][4] = {};

  // ---- prologue: tile0 full (8 calls) -> buf0; tile1 {A0,A2,B0-3} -> buf1
#pragma unroll
  for (int j = 0; j < 4; ++j) {
    stageA(j, 0, lA0);
    stageB(j, 0, lB0);
  }
  stageA(0, 1, lA0 + 16384);
  stageA(2, 1, lA0 + 16384);
#pragma unroll
  for (int j = 0; j < 4; ++j) stageB(j, 1, lB0 + 16384);
  __builtin_amdgcn_s_waitcnt(0x0f76);              // vmcnt(6): tile0 landed
  BAR();
  FENCE();

#pragma unroll 1
  for (int tt = 0; tt < 36; ++tt) {
    const int cb = (tt & 1) << 14;                 // buffer offset (shorts)
    const short* bufA = lA0 + cb;
    const short* bufB = lB0 + cb;
    short* oA = lA0 + (cb ^ 16384);
    short8 afLo[4], afHi[4], bf[4], bf2[4];

    // ============== free region: p0 + p1 + p2 (no barriers) ==============
    // p0: A-lo h0 + B h0; stage tt+1 {A1,A3} -> other buf
#pragma unroll
    for (int i = 0; i < 4; ++i) afLo[i] = *(const short8*)(bufA + aBase[0] + i * 1024);
#pragma unroll
    for (int i = 0; i < 4; ++i) bf[i] = *(const short8*)(bufB + bBase[0] + i * 1024);
    if (tt < 35) {
      stageA(1, tt + 1, oA);
      stageA(3, tt + 1, oA);
    }
    __builtin_amdgcn_s_setprio(1);
#pragma unroll
    for (int mi = 0; mi < 4; ++mi)
#pragma unroll
      for (int ni = 0; ni < 4; ++ni)
        acc[mi][ni] = __builtin_amdgcn_mfma_f32_16x16x32_bf16(afLo[mi], bf[ni], acc[mi][ni], 0, 0, 0);
    __builtin_amdgcn_s_setprio(0);

    // p1: A-hi h0
#pragma unroll
    for (int i = 0; i < 4; ++i) afHi[i] = *(const short8*)(bufA + aBase[0] + (4 + i) * 1024);
    __builtin_amdgcn_s_setprio(1);
#pragma unroll
    for (int mi = 0; mi < 4; ++mi)
#pragma unroll
      for (int ni = 0; ni < 4; ++ni)
        acc[4 + mi][ni] = __builtin_amdgcn_mfma_f32_16x16x32_bf16(afHi[mi], bf[ni], acc[4 + mi][ni], 0, 0, 0);
    __builtin_amdgcn_s_setprio(0);

    // p2: A-lo h1 + B h1
#pragma unroll
    for (int i = 0; i < 4; ++i) afLo[i] = *(const short8*)(bufA + aBase[1] + i * 1024);
#pragma unroll
    for (int i = 0; i < 4; ++i) bf2[i] = *(const short8*)(bufB + bBase[1] + i * 1024);
    __builtin_amdgcn_s_setprio(1);
#pragma unroll
    for (int mi = 0; mi < 4; ++mi)
#pragma unroll
      for (int ni = 0; ni < 4; ++ni)
        acc[mi][ni] = __builtin_amdgcn_mfma_f32_16x16x32_bf16(afLo[mi], bf2[ni], acc[mi][ni], 0, 0, 0);
    __builtin_amdgcn_s_setprio(0);

    // ============== BAR: cb's A0/A2/B reads done block-wide ==============
    BAR(); FENCE();

    // p3: A-hi h1 (rows disjoint from the stage below); stage tt+2
    // {A0,A2,B} -> cb; counted vmcnt covered by the final MFMA cluster.
#pragma unroll
    for (int i = 0; i < 4; ++i) afHi[i] = *(const short8*)(bufA + aBase[1] + (4 + i) * 1024);
    if (tt < 34) {
      stageA(0, tt + 2, lA0 + cb);
      stageA(2, tt + 2, lA0 + cb);
#pragma unroll
      for (int j = 0; j < 4; ++j) stageB(j, tt + 2, lB0 + cb);
    }
    if (tt < 34)       __builtin_amdgcn_s_waitcnt(0x0f76);  // vmcnt(6)
    else if (tt == 34) __builtin_amdgcn_s_waitcnt(0x0f70);  // vmcnt(0)
    FENCE();                                       // MFMAs stay below the wait
    __builtin_amdgcn_s_setprio(1);
#pragma unroll
    for (int mi = 0; mi < 4; ++mi)
#pragma unroll
      for (int ni = 0; ni < 4; ++ni)
        acc[4 + mi][ni] = __builtin_amdgcn_mfma_f32_16x16x32_bf16(afHi[mi], bf2[ni], acc[4 + mi][ni], 0, 0, 0);
    __builtin_amdgcn_s_setprio(0);
    if (tt < 35) { BAR(); FENCE(); }               // tt+1's buffer ready
  }

  // epilogue: D row(o) = quad*4 + r, col(hw) = lane&15  [verified m89/m91]
  const size_t outBase = (size_t)b * O_ * HW_;
#pragma unroll
  for (int mi = 0; mi < 8; ++mi) {
#pragma unroll
    for (int ni = 0; ni < 4; ++ni) {
      const int hw = hwBase + nW + ni * 16 + lm;
#pragma unroll
      for (int r = 0; r < 4; ++r) {
        const int o = mW + mi * 16 + quad * 4 + r;
        out[outBase + (size_t)o * HW_ + hw] = acc[mi][ni][r];
      }
    }
  }
}

// -------------------------------------------------------------- launch ------
extern "C" void kernel_launch(void* const* d_in, const int* in_sizes, int n_in,
                              void* d_out, int out_size, void* d_ws, size_t ws_size,
                              hipStream_t stream) {
  const float* x  = (const float*)d_in[0];   // [32,256,64,64]
  const float* w1 = (const float*)d_in[1];   // [65,256]
  const float* w2 = (const float*)d_in[2];   // [1024,65]
  const float* b2 = (const float*)d_in[3];   // [1024]
  const float* wt = (const float*)d_in[4];   // [4,256,256,3,3]
  float* out = (float*)d_out;                // [32,256,64,64]

  char* ws = (char*)d_ws;
  ushort_t* xpad = (ushort_t*)ws;                                  // 71.4 MB
  ushort_t* wagg = (ushort_t*)(ws + XPAD_ELEMS * 2);               // 37.7 MB
  float* partial = (float*)(ws + XPAD_ELEMS * 2 + WAGG_ELEMS * 2); // 2 MB
  float* attn    = partial + 64 * B_ * C_;                         // 128 KB

  pad_kernel<<<dim3(64, 4, B_), 256, 0, stream>>>(x, xpad, partial);
  attn_kernel<<<B_, 256, 0, stream>>>(partial, w1, w2, b2, attn);
  agg_kernel<<<dim3(O_, 8), 256, 0, stream>>>(attn, wt, wagg);
  gemm_kernel<<<512, 512, 0, stream>>>(xpad, wagg, out);
}